// Round 4
// baseline (416.179 us; speedup 1.0000x reference)
//
#include <hip/hip_runtime.h>

#define DEVI static __device__ __forceinline__

typedef __attribute__((ext_vector_type(8))) short bf16x8;
typedef __attribute__((ext_vector_type(4))) float f32x4;

DEVI ushort f2bf(float f) {
  union { float f; unsigned u; } v; v.f = f;
  unsigned r = v.u + 0x7fffu + ((v.u >> 16) & 1u);
  return (ushort)(r >> 16);
}
DEVI float bf2f(ushort u) {
  union { unsigned u; float f; } v; v.u = ((unsigned)u) << 16;
  return v.f;
}

// B=16, C=256, CI=128, N=4096 (64x64), M=1024 (32x32)
// ---- workspace layout (bytes) ----
#define WS_XT    0ull                      // bf16 [16][4096][256]
#define WS_WCAT  33554432ull               // bf16 [256][256] rows 0-127 phi_w, 128-255 g_w
#define WS_PG    (WS_WCAT + 131072ull)     // f32  [16][128][128]
#define WS_RST   (WS_PG + 1048576ull)      // bf16 [16][256][256]
#define WS_S     (WS_RST + 2097152ull)     // f32  [16][256]
#define WS_WY    (WS_S + 16384ull)         // bf16 [16][4096][256]
#define WS_SUM   (WS_WY + 33554432ull)     // f32 [256] sum + [256] sumsq
// phi/g (f32 [16][128][1024] each) overlay WY: dead before kwy writes WY
#define WS_PHI   WS_WY
#define WS_G     (WS_WY + 8388608ull)

// ---------------- P: transpose x -> xT bf16, prep conv weights, zero sums -------
__global__ __launch_bounds__(256) void kprep(
    const float* __restrict__ x, const float* __restrict__ phw,
    const float* __restrict__ gww, char* __restrict__ ws) {
  __shared__ float tile[64 * 65];
  const int bid = blockIdx.x, t = threadIdx.x;
  if (bid < 4096) {
    const int b = bid >> 8, rem = bid & 255;
    const int c0 = (rem >> 6) * 64, n0 = (rem & 63) * 64;
    const float* xb = x + ((size_t)(b * 256 + c0)) * 4096 + n0;
#pragma unroll
    for (int it = 0; it < 4; ++it) {
      int ch = t + it * 256;
      int cr = ch >> 4, nf = ch & 15;
      float4 v = *(const float4*)(xb + (size_t)cr * 4096 + nf * 4);
      tile[cr * 65 + nf * 4 + 0] = v.x;
      tile[cr * 65 + nf * 4 + 1] = v.y;
      tile[cr * 65 + nf * 4 + 2] = v.z;
      tile[cr * 65 + nf * 4 + 3] = v.w;
    }
    __syncthreads();
    ushort* xT = (ushort*)(ws + WS_XT);
#pragma unroll
    for (int it = 0; it < 2; ++it) {
      int ch = t + it * 256;
      int rn = ch >> 3, jc = ch & 7;
      uint4 pk;
      pk.x = (unsigned)f2bf(tile[(jc * 8 + 0) * 65 + rn]) | ((unsigned)f2bf(tile[(jc * 8 + 1) * 65 + rn]) << 16);
      pk.y = (unsigned)f2bf(tile[(jc * 8 + 2) * 65 + rn]) | ((unsigned)f2bf(tile[(jc * 8 + 3) * 65 + rn]) << 16);
      pk.z = (unsigned)f2bf(tile[(jc * 8 + 4) * 65 + rn]) | ((unsigned)f2bf(tile[(jc * 8 + 5) * 65 + rn]) << 16);
      pk.w = (unsigned)f2bf(tile[(jc * 8 + 6) * 65 + rn]) | ((unsigned)f2bf(tile[(jc * 8 + 7) * 65 + rn]) << 16);
      *(uint4*)(xT + ((size_t)(b * 4096 + n0 + rn)) * 256 + c0 + jc * 8) = pk;
    }
  } else if (bid == 4096) {
    ushort* Wcat = (ushort*)(ws + WS_WCAT);
    for (int idx = t; idx < 65536; idx += 256) {
      int ci = idx >> 8, c = idx & 255;
      float v = (ci < 128) ? phw[ci * 256 + c] : gww[(ci - 128) * 256 + c];
      Wcat[idx] = f2bf(v);
    }
  } else {
    float4 z = {0.f, 0.f, 0.f, 0.f};
    float4* st = (float4*)(ws + WS_SUM);
    if (t < 128) st[t] = z;
  }
}

// ------------- K1: phi/g conv (bf16 MFMA) + 2x2 maxpool + bias, store f32 [ci][m]
__global__ __launch_bounds__(256) void kconvpg(
    const float* __restrict__ phib, const float* __restrict__ gb,
    char* __restrict__ ws) {
  __shared__ __align__(16) char lds[49152];  // A: [128 n][64 c] 16KB, B: [256 ci][64 c] 32KB
  const int t = threadIdx.x;
  const int b = blockIdx.y, nb = blockIdx.x;
  const int n0 = nb * 128;
  const int lane = t & 63, wave = t >> 6;
  const int lr = lane & 15, lq = lane >> 4;
  const ushort* xT = (const ushort*)(ws + WS_XT) + ((size_t)(b * 4096 + n0)) * 256;
  const ushort* Wc = (const ushort*)(ws + WS_WCAT);

  f32x4 acc[8][4];
#pragma unroll
  for (int i = 0; i < 8; ++i)
#pragma unroll
    for (int j = 0; j < 4; ++j) acc[i][j] = (f32x4){0.f, 0.f, 0.f, 0.f};

  int4 ra[4], rb[8];
#pragma unroll
  for (int it = 0; it < 4; ++it) {
    int ch = t + it * 256, r = ch >> 3, jc = ch & 7;
    ra[it] = *(const int4*)(xT + (size_t)r * 256 + jc * 8);
  }
#pragma unroll
  for (int it = 0; it < 8; ++it) {
    int ch = t + it * 256, r = ch >> 3, jc = ch & 7;
    rb[it] = *(const int4*)(Wc + r * 256 + jc * 8);
  }
  const int swz = (lr & 7) << 4;

  for (int ks = 0; ks < 4; ++ks) {
#pragma unroll
    for (int it = 0; it < 4; ++it) {
      int ch = t + it * 256, r = ch >> 3, jc = ch & 7;
      *(int4*)(lds + r * 128 + ((jc * 16) ^ ((r & 7) << 4))) = ra[it];
    }
#pragma unroll
    for (int it = 0; it < 8; ++it) {
      int ch = t + it * 256, r = ch >> 3, jc = ch & 7;
      *(int4*)(lds + 16384 + r * 128 + ((jc * 16) ^ ((r & 7) << 4))) = rb[it];
    }
    __syncthreads();
    if (ks < 3) {
#pragma unroll
      for (int it = 0; it < 4; ++it) {
        int ch = t + it * 256, r = ch >> 3, jc = ch & 7;
        ra[it] = *(const int4*)(xT + (size_t)r * 256 + (ks + 1) * 64 + jc * 8);
      }
#pragma unroll
      for (int it = 0; it < 8; ++it) {
        int ch = t + it * 256, r = ch >> 3, jc = ch & 7;
        rb[it] = *(const int4*)(Wc + r * 256 + (ks + 1) * 64 + jc * 8);
      }
    }
#pragma unroll
    for (int k2 = 0; k2 < 2; ++k2) {
      const int kb = k2 * 64 + lq * 16;
      bf16x8 bfr[4];
#pragma unroll
      for (int j = 0; j < 4; ++j) {
        int bc = wave * 64 + j * 16 + lr;
        bfr[j] = *(const bf16x8*)(lds + 16384 + bc * 128 + (kb ^ swz));
      }
#pragma unroll
      for (int i = 0; i < 8; ++i) {
        int arw = i * 16 + lr;
        bf16x8 af = *(const bf16x8*)(lds + arw * 128 + (kb ^ swz));
#pragma unroll
        for (int j = 0; j < 4; ++j)
          acc[i][j] = __builtin_amdgcn_mfma_f32_16x16x32_bf16(af, bfr[j], acc[i][j], 0, 0, 0);
      }
    }
    __syncthreads();
  }
  // epilogue: pool rows (r, r+1) x (r+64, r+65), add bias, write f32 [ci][m]
#pragma unroll
  for (int j = 0; j < 4; ++j) {
    int cir = wave * 64 + j * 16 + lr;
    float bias;
    float* dst;
    if (cir < 128) {
      bias = phib[cir];
      dst = (float*)(ws + WS_PHI) + ((size_t)(b * 128 + cir)) * 1024;
    } else {
      bias = gb[cir - 128];
      dst = (float*)(ws + WS_G) + ((size_t)(b * 128 + cir - 128)) * 1024;
    }
    dst += nb * 32;
#pragma unroll
    for (int i = 0; i < 4; ++i) {
      f32x4 lo = acc[i][j], hi = acc[i + 4][j];
      float2 m;
      m.x = fmaxf(fmaxf(lo[0], lo[1]), fmaxf(hi[0], hi[1])) + bias;
      m.y = fmaxf(fmaxf(lo[2], lo[3]), fmaxf(hi[2], hi[3])) + bias;
      *(float2*)(dst + i * 8 + lq * 2) = m;
    }
  }
}

// ------------- K2a: PG[b][ci][cj] = sum_m phi[ci][m]*g[cj][m]  (fp32 VALU) ------
__global__ __launch_bounds__(256) void kpg32(char* __restrict__ ws) {
  __shared__ float lphi[32 * 65];
  __shared__ float lgd[32 * 65];
  const int t = threadIdx.x, b = blockIdx.y;
  const int cib = blockIdx.x >> 2, cjb = blockIdx.x & 3;
  const int ci_l = t >> 5, cj_l = t & 31;
  const float* phi = (const float*)(ws + WS_PHI) + ((size_t)(b * 128 + cib * 32)) * 1024;
  const float* gg = (const float*)(ws + WS_G) + ((size_t)(b * 128 + cjb * 32)) * 1024;
  float acc[4] = {0.f, 0.f, 0.f, 0.f};
  for (int kc = 0; kc < 16; ++kc) {
#pragma unroll
    for (int it = 0; it < 8; ++it) {
      int fi = t + it * 256;
      int r = fi >> 6, c = fi & 63;
      lphi[r * 65 + c] = phi[(size_t)r * 1024 + kc * 64 + c];
      lgd[r * 65 + c] = gg[(size_t)r * 1024 + kc * 64 + c];
    }
    __syncthreads();
#pragma unroll 8
    for (int k = 0; k < 64; ++k) {
      float gv = lgd[cj_l * 65 + k];
#pragma unroll
      for (int p = 0; p < 4; ++p)
        acc[p] += lphi[(ci_l * 4 + p) * 65 + k] * gv;
    }
    __syncthreads();
  }
  float* PG = (float*)(ws + WS_PG) + (size_t)b * 16384;
#pragma unroll
  for (int p = 0; p < 4; ++p)
    PG[(cib * 32 + ci_l * 4 + p) * 128 + cjb * 32 + cj_l] = acc[p];
}

// ------------- K2b: fused Qt -> Rst -> s, all fp32 VALU --------------------------
// Qt[c][i] = (1/1024) sum_j Ww[c][j]*PG[i][j]
// Rst[c][cp] = sum_i Qt[c][i]*thw[i][cp]   (bf16 out)
// s[c] = Wb[c] + sum_i thb[i]*Qt[c][i]
__global__ __launch_bounds__(256) void kmid(
    const float* __restrict__ thw, const float* __restrict__ thb,
    const float* __restrict__ wbias, const float* __restrict__ www,
    char* __restrict__ ws) {
  __shared__ __align__(16) char smid[49920];
  float* PGc = (float*)smid;             // [128][33] (phase 1)
  float* Wws = (float*)(smid + 16896);   // [32][129] (phase 1)
  float* Qts = (float*)(smid + 33408);   // [32][129]
  float* thws = (float*)smid;            // [128][65] (phase 2, overlays PGc+Wws)
  const int t = threadIdx.x, b = blockIdx.y, cblk = blockIdx.x;
  const int c_l = t >> 3, q = t & 7;
  const float* PGg = (const float*)(ws + WS_PG) + (size_t)b * 16384;

  // stage Ww rows for this c-block
#pragma unroll
  for (int it = 0; it < 16; ++it) {
    int fi = t + it * 256;
    int r = fi >> 7, j = fi & 127;
    Wws[r * 129 + j] = www[(cblk * 32 + r) * 128 + j];
  }
  float qacc[16];
#pragma unroll
  for (int i = 0; i < 16; ++i) qacc[i] = 0.f;

  for (int jc = 0; jc < 4; ++jc) {
#pragma unroll
    for (int it = 0; it < 16; ++it) {
      int fi = t + it * 256;
      int i = fi >> 5, jl = fi & 31;
      PGc[i * 33 + jl] = PGg[i * 128 + jc * 32 + jl];
    }
    __syncthreads();
#pragma unroll
    for (int iq = 0; iq < 16; ++iq) {
      int i = iq * 8 + q;
      float a = 0.f;
#pragma unroll 8
      for (int jl = 0; jl < 32; ++jl)
        a += Wws[c_l * 129 + jc * 32 + jl] * PGc[i * 33 + jl];
      qacc[iq] += a;
    }
    __syncthreads();
  }
  const float inv = 1.0f / 1024.0f;
#pragma unroll
  for (int iq = 0; iq < 16; ++iq) Qts[c_l * 129 + iq * 8 + q] = qacc[iq] * inv;
  __syncthreads();
  if (t < 32) {
    float sv = wbias[cblk * 32 + t];
    for (int i = 0; i < 128; ++i) sv += thb[i] * Qts[t * 129 + i];
    ((float*)(ws + WS_S))[b * 256 + cblk * 32 + t] = sv;
  }
  ushort* Rstb = (ushort*)(ws + WS_RST) + (size_t)b * 65536;
  for (int cpc = 0; cpc < 4; ++cpc) {
#pragma unroll
    for (int it = 0; it < 32; ++it) {
      int fi = t + it * 256;
      int i = fi >> 6, cp = fi & 63;
      thws[i * 65 + cp] = thw[i * 256 + cpc * 64 + cp];
    }
    __syncthreads();
#pragma unroll
    for (int k = 0; k < 8; ++k) {
      int cpl = q * 8 + k;
      float a = 0.f;
#pragma unroll 8
      for (int i = 0; i < 128; ++i)
        a += Qts[c_l * 129 + i] * thws[i * 65 + cpl];
      Rstb[(cblk * 32 + c_l) * 256 + cpc * 64 + cpl] = f2bf(a);
    }
    __syncthreads();
  }
}

// ------------- K3: w_y[b][n][c] = xT[n][:].Rst[c][:] + s[c]; fused channel stats --
__global__ __launch_bounds__(256) void kwy(char* __restrict__ ws) {
  __shared__ __align__(16) char lds[49152];  // A xT [128 n][64] 16KB, B Rst [256 c][64] 32KB
  const int t = threadIdx.x;
  const int b = blockIdx.y, nb = blockIdx.x;
  const int n0 = nb * 128;
  const int lane = t & 63, wave = t >> 6;
  const int lr = lane & 15, lq = lane >> 4;
  const ushort* xT = (const ushort*)(ws + WS_XT) + ((size_t)(b * 4096 + n0)) * 256;
  const ushort* Rst = (const ushort*)(ws + WS_RST) + (size_t)b * 65536;
  const float* sarr = (const float*)(ws + WS_S) + b * 256;
  float sreg[4];
#pragma unroll
  for (int j = 0; j < 4; ++j) sreg[j] = sarr[wave * 64 + j * 16 + lr];

  f32x4 acc[8][4];
#pragma unroll
  for (int i = 0; i < 8; ++i)
#pragma unroll
    for (int j = 0; j < 4; ++j) acc[i][j] = (f32x4){0.f, 0.f, 0.f, 0.f};

  int4 ra[4], rb[8];
#pragma unroll
  for (int it = 0; it < 4; ++it) {
    int ch = t + it * 256, r = ch >> 3, jc = ch & 7;
    ra[it] = *(const int4*)(xT + (size_t)r * 256 + jc * 8);
  }
#pragma unroll
  for (int it = 0; it < 8; ++it) {
    int ch = t + it * 256, r = ch >> 3, jc = ch & 7;
    rb[it] = *(const int4*)(Rst + r * 256 + jc * 8);
  }
  const int swz = (lr & 7) << 4;

  for (int ks = 0; ks < 4; ++ks) {
#pragma unroll
    for (int it = 0; it < 4; ++it) {
      int ch = t + it * 256, r = ch >> 3, jc = ch & 7;
      *(int4*)(lds + r * 128 + ((jc * 16) ^ ((r & 7) << 4))) = ra[it];
    }
#pragma unroll
    for (int it = 0; it < 8; ++it) {
      int ch = t + it * 256, r = ch >> 3, jc = ch & 7;
      *(int4*)(lds + 16384 + r * 128 + ((jc * 16) ^ ((r & 7) << 4))) = rb[it];
    }
    __syncthreads();
    if (ks < 3) {
#pragma unroll
      for (int it = 0; it < 4; ++it) {
        int ch = t + it * 256, r = ch >> 3, jc = ch & 7;
        ra[it] = *(const int4*)(xT + (size_t)r * 256 + (ks + 1) * 64 + jc * 8);
      }
#pragma unroll
      for (int it = 0; it < 8; ++it) {
        int ch = t + it * 256, r = ch >> 3, jc = ch & 7;
        rb[it] = *(const int4*)(Rst + r * 256 + (ks + 1) * 64 + jc * 8);
      }
    }
#pragma unroll
    for (int k2 = 0; k2 < 2; ++k2) {
      const int kb = k2 * 64 + lq * 16;
      bf16x8 bfr[4];
#pragma unroll
      for (int j = 0; j < 4; ++j) {
        int bc = wave * 64 + j * 16 + lr;
        bfr[j] = *(const bf16x8*)(lds + 16384 + bc * 128 + (kb ^ swz));
      }
#pragma unroll
      for (int i = 0; i < 8; ++i) {
        int arw = i * 16 + lr;
        bf16x8 af = *(const bf16x8*)(lds + arw * 128 + (kb ^ swz));
#pragma unroll
        for (int j = 0; j < 4; ++j)
          acc[i][j] = __builtin_amdgcn_mfma_f32_16x16x32_bf16(af, bfr[j], acc[i][j], 0, 0, 0);
      }
    }
    __syncthreads();
  }
  ushort* wyp = (ushort*)(ws + WS_WY) + ((size_t)(b * 4096 + n0)) * 256;
  float s1[4] = {0.f, 0.f, 0.f, 0.f}, s2[4] = {0.f, 0.f, 0.f, 0.f};
#pragma unroll
  for (int j = 0; j < 4; ++j) {
#pragma unroll
    for (int i = 0; i < 8; ++i) {
#pragma unroll
      for (int rr = 0; rr < 4; ++rr) {
        int ln = i * 16 + lq * 4 + rr;
        float v = acc[i][j][rr] + sreg[j];
        s1[j] += v;
        s2[j] += v * v;
        wyp[(size_t)ln * 256 + wave * 64 + j * 16 + lr] = f2bf(v);
      }
    }
  }
  float* gsum = (float*)(ws + WS_SUM);
  float* gsq = gsum + 256;
#pragma unroll
  for (int j = 0; j < 4; ++j) {
    float a = s1[j], qv = s2[j];
    a += __shfl_xor(a, 16);
    a += __shfl_xor(a, 32);
    qv += __shfl_xor(qv, 16);
    qv += __shfl_xor(qv, 32);
    if (lq == 0) {
      int c = wave * 64 + j * 16 + lr;
      atomicAdd(&gsum[c], a);
      atomicAdd(&gsq[c], qv);
    }
  }
}

// ------------- K5: out[b][c][n] = wy*scale[c] + shift[c] + x ---------------------
__global__ __launch_bounds__(256) void kout(
    const float* __restrict__ x, const float* __restrict__ gamma,
    const float* __restrict__ beta, const char* __restrict__ ws,
    float* __restrict__ out) {
  __shared__ float tile[256 * 35];
  __shared__ float scaleL[256], shiftL[256];
  const int t = threadIdx.x;
  const int b = blockIdx.y, n0 = blockIdx.x * 32;
  const ushort* wy = (const ushort*)(ws + WS_WY) + ((size_t)(b * 4096 + n0)) * 256;
#pragma unroll
  for (int it = 0; it < 4; ++it) {
    int ch = t + it * 256;
    int r = ch >> 5, j = ch & 31;
    bf16x8 v = *(const bf16x8*)(wy + (size_t)r * 256 + j * 8);
#pragma unroll
    for (int e = 0; e < 8; ++e) tile[(j * 8 + e) * 35 + r] = bf2f((ushort)v[e]);
  }
  {
    const float* gsum = (const float*)(ws + WS_SUM);
    float sm = gsum[t], sq = gsum[256 + t];
    float mean = sm * (1.0f / 65536.0f);
    float var = sq * (1.0f / 65536.0f) - mean * mean;
    float rs = rsqrtf(var + 1e-5f);
    float sc = gamma[t] * rs;
    scaleL[t] = sc;
    shiftL[t] = beta[t] - mean * sc;
  }
  __syncthreads();
  const float* xb = x + (size_t)b * 1048576 + n0;
  float* ob = out + (size_t)b * 1048576 + n0;
#pragma unroll
  for (int it = 0; it < 8; ++it) {
    int ch = t + it * 256;
    int c = ch >> 3, nj = ch & 7;
    float4 xv = *(const float4*)(xb + (size_t)c * 4096 + nj * 4);
    float sc = scaleL[c], sh = shiftL[c];
    float4 ov;
    ov.x = tile[c * 35 + nj * 4 + 0] * sc + sh + xv.x;
    ov.y = tile[c * 35 + nj * 4 + 1] * sc + sh + xv.y;
    ov.z = tile[c * 35 + nj * 4 + 2] * sc + sh + xv.z;
    ov.w = tile[c * 35 + nj * 4 + 3] * sc + sh + xv.w;
    *(float4*)(ob + (size_t)c * 4096 + nj * 4) = ov;
  }
}

extern "C" void kernel_launch(void* const* d_in, const int* in_sizes, int n_in,
                              void* d_out, int out_size, void* d_ws, size_t ws_size,
                              hipStream_t stream) {
  const float* x = (const float*)d_in[0];
  const float* thw = (const float*)d_in[1];
  const float* thb = (const float*)d_in[2];
  const float* phw = (const float*)d_in[3];
  const float* phb = (const float*)d_in[4];
  const float* gw = (const float*)d_in[5];
  const float* gb = (const float*)d_in[6];
  const float* www = (const float*)d_in[7];
  const float* wwb = (const float*)d_in[8];
  const float* gamma = (const float*)d_in[9];
  const float* beta = (const float*)d_in[10];
  char* ws = (char*)d_ws;
  float* out = (float*)d_out;

  kprep<<<dim3(4098), dim3(256), 0, stream>>>(x, phw, gw, ws);
  kconvpg<<<dim3(32, 16), dim3(256), 0, stream>>>(phb, gb, ws);
  kpg32<<<dim3(16, 16), dim3(256), 0, stream>>>(ws);
  kmid<<<dim3(8, 16), dim3(256), 0, stream>>>(thw, thb, wwb, www, ws);
  kwy<<<dim3(32, 16), dim3(256), 0, stream>>>(ws);
  kout<<<dim3(128, 16), dim3(256), 0, stream>>>(x, gamma, beta, ws, out);
}